// Round 2
// baseline (651.876 us; speedup 1.0000x reference)
//
#include <hip/hip_runtime.h>
#include <hip/hip_bf16.h>

#define BB 2
#define NN 2000
#define GG 100
#define HH 800
#define WW 800
#define TT 200
#define PP 66
#define NEGN 134
#define MHH 28
#define MWW 28

// workspace layout (byte offsets)
#define WS_IOU 0            // float[B*N]
#define WS_AMAX 16000       // int[B*N]
#define WS_FLAGS 32000      // int[B*N]
#define WS_POSIDX 48000     // int[B*P]
#define WS_NEGIDX 50048     // int[B*NEG]
#define WS_MODES 52096      // int[2]: [0]=mask mode, [1]=box mode

enum { M_F32 = 0, M_BF16 = 1, M_I32 = 2, M_U8 = 3 };

__device__ __forceinline__ float bf16_to_f(unsigned short v) {
  return __uint_as_float(((unsigned int)v) << 16);
}

__device__ __forceinline__ float load_box_c(const void* p, long long elem, int mode) {
  if (mode == M_BF16) return bf16_to_f(((const unsigned short*)p)[elem]);
  return ((const float*)p)[elem];
}

__device__ __forceinline__ float load_mask(const void* p, size_t idx, int mode) {
  switch (mode) {
    case M_F32:  return ((const float*)p)[idx];
    case M_BF16: return ((const unsigned short*)p)[idx] ? 1.0f : 0.0f;
    case M_I32:  return ((const int*)p)[idx] ? 1.0f : 0.0f;
    default:     return ((const unsigned char*)p)[idx] ? 1.0f : 0.0f;
  }
}

// ---- dtype sniffer: decides how gt_masks / proposals+gt_boxes are encoded ----
__global__ void detect_modes(const unsigned int* props, const unsigned int* masks,
                             int* modes) {
  __shared__ int cnt[5];
  int tid = threadIdx.x;
  if (tid < 5) cnt[tid] = 0;
  __syncthreads();
  int lf = 0, lb = 0, li = 0, lu = 0, lbox = 0;
  for (int i = tid; i < 4096; i += 256) {   // masks buffer: >=128MB in every candidate encoding
    unsigned int w = masks[i];
    if (w == 0u || w == 0x3F800000u) lf++;
    unsigned int lo = w & 0xFFFFu, hi = w >> 16;
    if ((lo == 0u || lo == 0x3F80u) && (hi == 0u || hi == 0x3F80u)) lb++;
    if (w <= 1u) li++;
    if ((w & 0xFEFEFEFEu) == 0u) lu++;      // all 4 bytes in {0,1}
  }
  for (int i = tid; i < 4000; i += 256) {   // proposals buffer: >=32000B even if bf16
    unsigned int w = props[i];
    float flo = bf16_to_f((unsigned short)(w & 0xFFFFu));
    float fhi = bf16_to_f((unsigned short)(w >> 16));
    if (flo >= 0.0f && flo <= 4.0f && fhi >= 0.0f && fhi <= 4.0f) lbox++;
  }
  atomicAdd(&cnt[0], lf); atomicAdd(&cnt[1], lb); atomicAdd(&cnt[2], li);
  atomicAdd(&cnt[3], lu); atomicAdd(&cnt[4], lbox);
  __syncthreads();
  if (tid == 0) {
    int mm;
    if (cnt[0] >= 4055) mm = M_F32;         // f32 data satisfies bf16 test too: check f32 first
    else if (cnt[1] >= 4055) mm = M_BF16;
    else if (cnt[2] >= 4055) mm = M_I32;    // i32 data satisfies u8 test too: check i32 first
    else mm = M_U8;
    modes[0] = mm;
    modes[1] = (cnt[4] >= 2800) ? M_BF16 : M_F32;
  }
}

// ---- per-proposal IoU max / argmax / pos,neg flags ----
__global__ void iou_kernel(const void* props, const int* cls, const void* gtb,
                           const int* modes, float* iou_max, int* amax, int* flags) {
#pragma clang fp contract(off)
  int idx = blockIdx.x * blockDim.x + threadIdx.x;
  if (idx >= BB * NN) return;
  int bmode = modes[1];
  int b = idx / NN, i = idx - b * NN;
  long long e = (long long)(b * NN + i) * 4;
  float p0 = load_box_c(props, e + 0, bmode);
  float p1 = load_box_c(props, e + 1, bmode);
  float p2 = load_box_c(props, e + 2, bmode);
  float p3 = load_box_c(props, e + 3, bmode);
  float a1 = (p2 - p0) * (p3 - p1);
  float best = -1e30f; int bestg = 0; float crowdmax = -1.0f;
  for (int g = 0; g < GG; ++g) {
    long long ge = (long long)(b * GG + g) * 4;
    float g0 = load_box_c(gtb, ge + 0, bmode);
    float g1 = load_box_c(gtb, ge + 1, bmode);
    float g2 = load_box_c(gtb, ge + 2, bmode);
    float g3 = load_box_c(gtb, ge + 3, bmode);
    float yy1 = fmaxf(p0, g0), xx1 = fmaxf(p1, g1);
    float yy2 = fminf(p2, g2), xx2 = fminf(p3, g3);
    float ih = yy2 - yy1; if (ih < 0.0f) ih = 0.0f;
    float iw = xx2 - xx1; if (iw < 0.0f) iw = 0.0f;
    float inter = ih * iw;
    float a2 = (g2 - g0) * (g3 - g1);
    float uni = (a1 + a2) - inter;
    float iou = inter / fmaxf(uni, 1e-12f);
    bool crowd = cls[b * GG + g] < 0;
    float ov = crowd ? -1.0f : iou;
    if (ov > best) { best = ov; bestg = g; }   // strict > == jnp.argmax first-max
    float cv = crowd ? iou : -1.0f;
    if (cv > crowdmax) crowdmax = cv;
  }
  iou_max[idx] = best;
  amax[idx] = bestg;
  int f = 0;
  if (best >= 0.5f) f |= 1;
  if (best < 0.5f && crowdmax < 0.001f) f |= 2;
  flags[idx] = f;
}

__device__ __forceinline__ unsigned int ord_f32(float f) {
  unsigned int u = __float_as_uint(f);
  return (u & 0x80000000u) ? ~u : (u | 0x80000000u);
}

// ---- stable top-k via full bitonic sort of (value desc, index asc) keys ----
__global__ void __launch_bounds__(1024)
select_kernel(const float* iou, const int* flags, int* posidx, int* negidx) {
  __shared__ unsigned long long keys[2048];
  int b = blockIdx.x >> 1;
  int which = blockIdx.x & 1;   // 0 = positives, 1 = negatives
  int tid = threadIdx.x;
  for (int i = tid; i < 2048; i += 1024) {
    unsigned long long k = 0ull;
    if (i < NN) {
      int f = flags[b * NN + i];
      bool ok = which == 0 ? ((f & 1) != 0) : ((f & 2) != 0);
      float v = ok ? iou[b * NN + i] : -1.0f;           // matches jnp.where(cond, val, -1.0)
      k = (((unsigned long long)ord_f32(v)) << 32) | (unsigned long long)(2047 - i);
    }
    keys[i] = k;
  }
  __syncthreads();
  for (int kk = 2; kk <= 2048; kk <<= 1) {
    for (int j = kk >> 1; j > 0; j >>= 1) {
      for (int i = tid; i < 2048; i += 1024) {
        int ixj = i ^ j;
        if (ixj > i) {
          unsigned long long a = keys[i], c = keys[ixj];
          bool up = ((i & kk) == 0);
          if (up ? (a < c) : (a > c)) { keys[i] = c; keys[ixj] = a; }  // descending sort
        }
      }
      __syncthreads();
    }
  }
  int cnt = which == 0 ? PP : NEGN;
  int* dst = which == 0 ? (posidx + b * PP) : (negidx + b * NEGN);
  for (int t = tid; t < cnt; t += 1024)
    dst[t] = 2047 - (int)(keys[t] & 0xFFFFFFFFull);
}

// ---- rois / class_ids / deltas (FLOAT32 output) ----
__global__ void emit_kernel(const void* props, const int* cls, const void* gtb,
                            const int* modes, const int* flags, const int* amax,
                            const int* posidx, const int* negidx, float* out) {
#pragma clang fp contract(off)
  int id = blockIdx.x * blockDim.x + threadIdx.x;
  if (id >= BB * TT) return;
  int bmode = modes[1];
  int b = id / TT, t = id - b * TT;
  float r0 = 0, r1 = 0, r2 = 0, r3 = 0;
  float d0 = 0, d1 = 0, d2 = 0, d3 = 0;
  float cid = 0.0f;
  if (t < PP) {
    int i = posidx[b * PP + t];
    bool ok = (flags[b * NN + i] & 1) != 0;
    long long e = (long long)(b * NN + i) * 4;
    float p0 = load_box_c(props, e + 0, bmode), p1 = load_box_c(props, e + 1, bmode);
    float p2 = load_box_c(props, e + 2, bmode), p3 = load_box_c(props, e + 3, bmode);
    if (ok) {
      r0 = p0; r1 = p1; r2 = p2; r3 = p3;
      int g = amax[b * NN + i];
      cid = (float)cls[b * GG + g];
      long long ge = (long long)(b * GG + g) * 4;
      float g0 = load_box_c(gtb, ge + 0, bmode), g1 = load_box_c(gtb, ge + 1, bmode);
      float g2 = load_box_c(gtb, ge + 2, bmode), g3 = load_box_c(gtb, ge + 3, bmode);
      float h = p2 - p0, w = p3 - p1;
      float cy = p0 + 0.5f * h, cx = p1 + 0.5f * w;
      float gh = g2 - g0, gw = g3 - g1;
      float gcy = g0 + 0.5f * gh, gcx = g1 + 0.5f * gw;
      d0 = ((gcy - cy) / h) / 0.1f;
      d1 = ((gcx - cx) / w) / 0.1f;
      d2 = logf(gh / h) / 0.2f;
      d3 = logf(gw / w) / 0.2f;
    }
  } else {
    int j = negidx[b * NEGN + (t - PP)];
    bool ok = (flags[b * NN + j] & 2) != 0;
    if (ok) {
      long long e = (long long)(b * NN + j) * 4;
      r0 = load_box_c(props, e + 0, bmode); r1 = load_box_c(props, e + 1, bmode);
      r2 = load_box_c(props, e + 2, bmode); r3 = load_box_c(props, e + 3, bmode);
    }
  }
  int rb = (b * TT + t) * 4;
  out[rb + 0] = r0;
  out[rb + 1] = r1;
  out[rb + 2] = r2;
  out[rb + 3] = r3;
  out[1600 + b * TT + t] = cid;
  int db = 2000 + (b * TT + t) * 4;
  out[db + 0] = d0;
  out[db + 1] = d1;
  out[db + 2] = d2;
  out[db + 3] = d3;
}

// ---- 28x28 bilinear mask crops (FLOAT32 output) ----
__global__ void mask_kernel(const void* props, const void* gmask, const int* modes,
                            const int* flags, const int* amax, const int* posidx,
                            float* out) {
#pragma clang fp contract(off)
  int blk = blockIdx.x;                 // b*T + t
  int b = blk / TT, t = blk - b * TT;
  float* mout = out + 3600 + (size_t)blk * (MHH * MWW);
  bool ok = false; int g = 0;
  float by1 = 0, bx1 = 0, by2 = 0, bx2 = 0;
  if (t < PP) {
    int i = posidx[b * PP + t];
    ok = (flags[b * NN + i] & 1) != 0;
    g = amax[b * NN + i];
    int bmode = modes[1];
    long long e = (long long)(b * NN + i) * 4;
    by1 = load_box_c(props, e + 0, bmode); bx1 = load_box_c(props, e + 1, bmode);
    by2 = load_box_c(props, e + 2, bmode); bx2 = load_box_c(props, e + 3, bmode);
  }
  if (!ok) {
    for (int p = threadIdx.x; p < MHH * MWW; p += blockDim.x)
      mout[p] = 0.0f;
    return;
  }
  int mmode = modes[0];
  for (int p = threadIdx.x; p < MHH * MWW; p += blockDim.x) {
    int yy = p / MWW, xx = p - yy * MWW;
    // ys = by1*(H-1) + ((i/(MH-1)) * (by2-by1)) * (H-1)   — exact op order of reference
    float ty = (float)yy / 27.0f;
    float ys = by1 * 799.0f + (ty * (by2 - by1)) * 799.0f;
    float tx = (float)xx / 27.0f;
    float xs = bx1 * 799.0f + (tx * (bx2 - bx1)) * 799.0f;
    float y0f = floorf(ys), x0f = floorf(xs);
    float wy = ys - y0f, wx = xs - x0f;
    int y0 = (int)y0f; if (y0 < 0) y0 = 0; if (y0 > HH - 1) y0 = HH - 1;
    int y1 = y0 + 1;   if (y1 > HH - 1) y1 = HH - 1;
    int x0 = (int)x0f; if (x0 < 0) x0 = 0; if (x0 > WW - 1) x0 = WW - 1;
    int x1 = x0 + 1;   if (x1 > WW - 1) x1 = WW - 1;
    size_t rowb = (size_t)b * HH;
    size_t i00 = ((rowb + y0) * WW + x0) * GG + g;
    size_t i01 = ((rowb + y0) * WW + x1) * GG + g;
    size_t i10 = ((rowb + y1) * WW + x0) * GG + g;
    size_t i11 = ((rowb + y1) * WW + x1) * GG + g;
    float v00 = load_mask(gmask, i00, mmode);
    float v01 = load_mask(gmask, i01, mmode);
    float v10 = load_mask(gmask, i10, mmode);
    float v11 = load_mask(gmask, i11, mmode);
    float top = v00 * (1.0f - wx) + v01 * wx;
    float bot = v10 * (1.0f - wx) + v11 * wx;
    float m = top * (1.0f - wy) + bot * wy;
    m = rintf(m);                       // jnp.round = round-half-to-even
    mout[p] = m;
  }
}

extern "C" void kernel_launch(void* const* d_in, const int* in_sizes, int n_in,
                              void* d_out, int out_size, void* d_ws, size_t ws_size,
                              hipStream_t stream) {
  const void* props = d_in[0];
  const int* cls = (const int*)d_in[1];
  const void* gtb = d_in[2];
  const void* gmask = d_in[3];
  char* ws = (char*)d_ws;
  float* iou   = (float*)(ws + WS_IOU);
  int* amax    = (int*)(ws + WS_AMAX);
  int* flags   = (int*)(ws + WS_FLAGS);
  int* posidx  = (int*)(ws + WS_POSIDX);
  int* negidx  = (int*)(ws + WS_NEGIDX);
  int* modes   = (int*)(ws + WS_MODES);
  float* out = (float*)d_out;

  detect_modes<<<1, 256, 0, stream>>>((const unsigned int*)props,
                                      (const unsigned int*)gmask, modes);
  iou_kernel<<<(BB * NN + 255) / 256, 256, 0, stream>>>(props, cls, gtb, modes,
                                                        iou, amax, flags);
  select_kernel<<<BB * 2, 1024, 0, stream>>>(iou, flags, posidx, negidx);
  emit_kernel<<<(BB * TT + 255) / 256, 256, 0, stream>>>(props, cls, gtb, modes,
                                                         flags, amax, posidx, negidx, out);
  mask_kernel<<<BB * TT, 256, 0, stream>>>(props, gmask, modes, flags, amax, posidx, out);
}